// Round 1
// 349.091 us; speedup vs baseline: 1.0077x; 1.0077x over previous
//
#include <hip/hip_runtime.h>
#include <math.h>

#define IMG 128
#define CDIM 256
#define NHEADS 8
#define DHEAD 32

typedef _Float16 half8 __attribute__((ext_vector_type(8)));
typedef _Float16 half4 __attribute__((ext_vector_type(4)));
typedef float floatx4 __attribute__((ext_vector_type(4)));

// ==================== one-time weight transposes (f32 -> f16) ==============
// w: [256][256] row-major (k rows, n cols) -> wT: [n][k] f16
__global__ __launch_bounds__(256) void transpose_w_kernel(
    const float* __restrict__ w, _Float16* __restrict__ wT)
{
  const int n = blockIdx.x;
  const int k = threadIdx.x;
  wT[(size_t)n * 256 + k] = (_Float16)w[(size_t)k * 256 + n];
}

// conv weights: (25*32, 512) f32 -> wT: (8, 25, 64, 32) f16
__global__ __launch_bounds__(512) void wt_kernel(const float* __restrict__ w,
                                                 _Float16* __restrict__ wT)
{
  const int tap = blockIdx.x;          // 0..24
  const int t = threadIdx.x;           // 0..511 = global oc
  const int g = t >> 6, o = t & 63;
  _Float16 h[32];
#pragma unroll
  for (int ic = 0; ic < 32; ic++)
    h[ic] = (_Float16)w[(size_t)(tap * 32 + ic) * 512 + t];
  half8* dst = (half8*)(wT + (((size_t)g * 25 + tap) * 64 + o) * 32);
#pragma unroll
  for (int i = 0; i < 4; i++) dst[i] = *(half8*)(h + i * 8);
}

// ==================== MFMA GEMM: C = scale*(A@B + bias) ====================
// A: M x 256 (fp32 or f16 per AF16), BT: [n][k] f16 (pre-transposed weights),
// C: M x 256 (f16 or fp32 per OUTF16). Block = 128x128 C-tile, 4 waves.
#define GSTR 40   // LDS row stride in f16 (32 data + 8 pad)

template <bool AF16, bool OUTF16>
__global__ __launch_bounds__(256) void gemm_mfma_kernel(
    const void* __restrict__ Ap, const _Float16* __restrict__ BT,
    const float* __restrict__ bias, const float* __restrict__ scale_ptr,
    void* __restrict__ Cp)
{
  __shared__ _Float16 As[128 * GSTR];   // 10240 B
  __shared__ _Float16 Bs[128 * GSTR];   // 10240 B

  const int tid = threadIdx.x;
  const int m0 = blockIdx.x * 128;
  const int n0 = blockIdx.y * 128;
  const int wave = tid >> 6, lane = tid & 63;
  const int lq = lane & 15, quad = lane >> 4;
  const int wm = (wave >> 1) * 64, wn = (wave & 1) * 64;

  floatx4 acc[4][4];
#pragma unroll
  for (int i = 0; i < 4; i++)
#pragma unroll
    for (int j = 0; j < 4; j++) acc[i][j] = (floatx4){0.f, 0.f, 0.f, 0.f};

  for (int kc = 0; kc < 8; kc++) {
    const int k0 = kc * 32;
    __syncthreads();
    if (AF16) {
      const _Float16* A = (const _Float16*)Ap;
#pragma unroll
      for (int r = 0; r < 2; r++) {
        int idx = tid + r * 256;               // 0..511
        int row = idx >> 2, c8 = (idx & 3) * 8;
        *(half8*)(As + row * GSTR + c8) =
            *(const half8*)(A + (size_t)(m0 + row) * 256 + k0 + c8);
      }
    } else {
      const float* A = (const float*)Ap;
#pragma unroll
      for (int r = 0; r < 4; r++) {
        int idx = tid + r * 256;               // 0..1023
        int row = idx >> 3, c4 = (idx & 7) * 4;
        float4 v = *(const float4*)(A + (size_t)(m0 + row) * 256 + k0 + c4);
        half4 h;
        h[0] = (_Float16)v.x; h[1] = (_Float16)v.y;
        h[2] = (_Float16)v.z; h[3] = (_Float16)v.w;
        *(half4*)(As + row * GSTR + c4) = h;
      }
    }
#pragma unroll
    for (int r = 0; r < 2; r++) {
      int idx = tid + r * 256;
      int row = idx >> 2, c8 = (idx & 3) * 8;
      *(half8*)(Bs + row * GSTR + c8) =
          *(const half8*)(BT + (size_t)(n0 + row) * 256 + k0 + c8);
    }
    __syncthreads();

    half8 aF[4], bF[4];
#pragma unroll
    for (int i = 0; i < 4; i++) {
      aF[i] = *(const half8*)(As + (wm + i * 16 + lq) * GSTR + quad * 8);
      bF[i] = *(const half8*)(Bs + (wn + i * 16 + lq) * GSTR + quad * 8);
    }
#pragma unroll
    for (int mt = 0; mt < 4; mt++)
#pragma unroll
      for (int nt = 0; nt < 4; nt++)
        acc[mt][nt] = __builtin_amdgcn_mfma_f32_16x16x32_f16(
            aF[mt], bF[nt], acc[mt][nt], 0, 0, 0);
  }

  const float s = scale_ptr ? scale_ptr[0] : 1.0f;
#pragma unroll
  for (int nt = 0; nt < 4; nt++) {
    const int n = n0 + wn + nt * 16 + lq;
    const float bv = bias[n];
#pragma unroll
    for (int mt = 0; mt < 4; mt++) {
      const int mbase = m0 + wm + mt * 16 + quad * 4;
#pragma unroll
      for (int r = 0; r < 4; r++) {
        float val = s * (acc[mt][nt][r] + bv);
        if (OUTF16)
          ((_Float16*)Cp)[(size_t)(mbase + r) * 256 + n] = (_Float16)val;
        else
          ((float*)Cp)[(size_t)(mbase + r) * 256 + n] = val;
      }
    }
  }
}

// ==================== grouped 5x5 conv via implicit-GEMM MFMA ==============
// Restructured: weights are read directly from global (L2-resident, perfectly
// coalesced 1KB/fragment) instead of staged through LDS.
//   - kills the 8-way bank conflict on the old wsl reads (64B row stride)
//   - kills 5 weight re-stagings + 10 of 11 __syncthreads per block
//   - LDS drops 52.7KB -> 32KB: 4 blocks/CU instead of 2 (latency hiding)
#define PS 40   // patch pixel stride in f16 (32 data + 8 pad -> 2-way = free)
#define PW 20

__global__ __launch_bounds__(256, 4) void conv_mfma_kernel(
    const float* __restrict__ xin, const _Float16* __restrict__ wT,
    const float* __restrict__ bias, _Float16* __restrict__ kvout)
{
  __shared__ _Float16 patch[400 * PS];    // 32000 B

  const int tid  = threadIdx.x;
  const int tile = blockIdx.x;
  const int g    = blockIdx.y;
  const int b    = blockIdx.z;
  const int ty0 = (tile >> 3) * 16, tx0 = (tile & 7) * 16;

  for (int idx = tid; idx < 800; idx += 256) {
    int pix = idx >> 1, c0 = (idx & 1) * 16;
    int py = pix / 20, px = pix - py * 20;
    int gy = ty0 + py - 2, gx = tx0 + px - 2;
    _Float16 h[16];
    if ((unsigned)gy < (unsigned)IMG && (unsigned)gx < (unsigned)IMG) {
      const float4* src = (const float4*)(xin + ((((size_t)b * IMG + gy) * IMG) + gx) * CDIM + g * 32 + c0);
#pragma unroll
      for (int i = 0; i < 4; i++) {
        float4 v = src[i];
        h[i * 4 + 0] = (_Float16)v.x; h[i * 4 + 1] = (_Float16)v.y;
        h[i * 4 + 2] = (_Float16)v.z; h[i * 4 + 3] = (_Float16)v.w;
      }
    } else {
#pragma unroll
      for (int i = 0; i < 16; i++) h[i] = (_Float16)0.f;
    }
    *(half8*)(patch + pix * PS + c0)     = *(half8*)h;
    *(half8*)(patch + pix * PS + c0 + 8) = *(half8*)(h + 8);
  }

  const int wave = tid >> 6, lane = tid & 63;
  const int lq = lane & 15, quad = lane >> 4;

  floatx4 acc[4][4];
#pragma unroll
  for (int i = 0; i < 4; i++)
#pragma unroll
    for (int j = 0; j < 4; j++) acc[i][j] = (floatx4){0.f, 0.f, 0.f, 0.f};

  // per-lane weight base: fragment element (oc=mt*16+lq, ic=quad*8..+8)
  // matches the wT global layout exactly -> coalesced 1KB dwordx4 loads.
  const _Float16* wg = wT + (size_t)g * 25 * 64 * 32 + (size_t)lq * 32 + quad * 8;

  __syncthreads();

  for (int ky = 0; ky < 5; ky++) {
#pragma unroll
    for (int kx = 0; kx < 5; kx++) {
      half8 bfr[4];
#pragma unroll
      for (int nt = 0; nt < 4; nt++) {
        int py = wave * 4 + nt + ky;
        bfr[nt] = *(const half8*)(patch + (py * PW + lq + kx) * PS + quad * 8);
      }
      const _Float16* wk = wg + (size_t)((ky * 5 + kx) * 64) * 32;
#pragma unroll
      for (int mt = 0; mt < 4; mt++) {
        half8 afr = *(const half8*)(wk + mt * 16 * 32);
#pragma unroll
        for (int nt = 0; nt < 4; nt++)
          acc[mt][nt] = __builtin_amdgcn_mfma_f32_16x16x32_f16(afr, bfr[nt], acc[mt][nt], 0, 0, 0);
      }
    }
  }

#pragma unroll
  for (int mt = 0; mt < 4; mt++) {
    float4 bv = *(const float4*)(bias + g * 64 + mt * 16 + quad * 4);
#pragma unroll
    for (int nt = 0; nt < 4; nt++) {
      int oy = ty0 + wave * 4 + nt;
      int ox = tx0 + lq;
      half4 ov;
      ov[0] = (_Float16)(acc[mt][nt][0] + bv.x);
      ov[1] = (_Float16)(acc[mt][nt][1] + bv.y);
      ov[2] = (_Float16)(acc[mt][nt][2] + bv.z);
      ov[3] = (_Float16)(acc[mt][nt][3] + bv.w);
      *(half4*)(kvout + ((((size_t)b * IMG + oy) * IMG) + ox) * 512 + g * 64 + mt * 16 + quad * 4) = ov;
    }
  }
}

// ====================== MFMA flash attention (S^T trick) ===================
#define KSTR 40    // K row stride in f16
#define VSTR 264   // Vt row stride in f16

__global__ __launch_bounds__(256, 3) void attn_mfma_kernel(
    _Float16* __restrict__ qf, const _Float16* __restrict__ kv,
    const float* __restrict__ bias_table)
{
  __shared__ _Float16 Kl[256 * KSTR];
  __shared__ _Float16 Vt[32 * VSTR];
  __shared__ float bsm[961];

  const int tid = threadIdx.x;
  const int n  = blockIdx.x;
  const int hh = blockIdx.y;
  const int b  = n >> 6;
  const int wy = (n >> 3) & 7;
  const int wx = n & 7;
  const int y0 = wy * 16, x0 = wx * 16;

  for (int i = tid; i < 961; i += 256) bsm[i] = bias_table[i * 8 + hh];

  {
    const int ty = tid >> 4, tx = tid & 15;
    size_t base = ((((size_t)b * IMG + y0 + ty) * IMG) + x0 + tx) * 512;
    const half8* kp = (const half8*)(kv + base + hh * 32);
    const half8* vp = (const half8*)(kv + base + 256 + hh * 32);
#pragma unroll
    for (int i = 0; i < 4; i++)
      *(half8*)(Kl + tid * KSTR + i * 8) = kp[i];
    half8 vh[4];
#pragma unroll
    for (int i = 0; i < 4; i++) vh[i] = vp[i];
#pragma unroll
    for (int i = 0; i < 4; i++)
#pragma unroll
      for (int j = 0; j < 8; j++)
        Vt[(i * 8 + j) * VSTR + tid] = vh[i][j];
  }

  const int wave = tid >> 6, lane = tid & 63;
  const int lq = lane & 15, quad = lane >> 4;

  half8 qB[4];
  int qbase[4];
  size_t qptr[4];
#pragma unroll
  for (int qt = 0; qt < 4; qt++) {
    int tok = wave * 64 + qt * 16 + lq;
    int qy = tok >> 4, qx = tok & 15;
    qbase[qt] = (qy + 15) * 31 + (qx + 15);
    size_t p = ((((size_t)b * IMG + y0 + qy) * IMG) + x0 + qx) * CDIM + hh * 32;
    qptr[qt] = p;
    qB[qt] = *(const half8*)(qf + p + quad * 8);
  }

  __syncthreads();

  float m[4] = {-1e30f, -1e30f, -1e30f, -1e30f};
  float l[4] = {0.f, 0.f, 0.f, 0.f};
  floatx4 Ot[2][4];
#pragma unroll
  for (int dt = 0; dt < 2; dt++)
#pragma unroll
    for (int qt = 0; qt < 4; qt++) Ot[dt][qt] = (floatx4){0.f, 0.f, 0.f, 0.f};

  const float scale = 0.17677669529663687f;

  for (int ch = 0; ch < 8; ch++) {
    half8 kA[2];
#pragma unroll
    for (int kt = 0; kt < 2; kt++)
      kA[kt] = *(const half8*)(Kl + (ch * 32 + kt * 16 + lq) * KSTR + quad * 8);

    floatx4 S[4][2];
#pragma unroll
    for (int qt = 0; qt < 4; qt++)
#pragma unroll
      for (int kt = 0; kt < 2; kt++)
        S[qt][kt] = __builtin_amdgcn_mfma_f32_16x16x32_f16(
            kA[kt], qB[qt], (floatx4){0.f, 0.f, 0.f, 0.f}, 0, 0, 0);

    half4 vA[2][2];
#pragma unroll
    for (int dt = 0; dt < 2; dt++)
#pragma unroll
      for (int kt = 0; kt < 2; kt++)
        vA[dt][kt] = *(const half4*)(Vt + (dt * 16 + lq) * VSTR +
                                     ch * 32 + kt * 16 + quad * 4);

    half4 pB[4][2];
#pragma unroll
    for (int qt = 0; qt < 4; qt++) {
      float sv[8];
#pragma unroll
      for (int kt = 0; kt < 2; kt++) {
        int keybase = ch * 32 + kt * 16 + quad * 4;
        int koff = (keybase >> 4) * 31 + (keybase & 15);
#pragma unroll
        for (int r = 0; r < 4; r++)
          sv[kt * 4 + r] = S[qt][kt][r] * scale + bsm[qbase[qt] - koff - r];
      }
      float mx = sv[0];
#pragma unroll
      for (int i = 1; i < 8; i++) mx = fmaxf(mx, sv[i]);
      mx = fmaxf(mx, __shfl_xor(mx, 16));
      mx = fmaxf(mx, __shfl_xor(mx, 32));
      float mn = fmaxf(m[qt], mx);
      float c = __expf(m[qt] - mn);
      m[qt] = mn;
      float ps = 0.f;
#pragma unroll
      for (int i = 0; i < 8; i++) { sv[i] = __expf(sv[i] - mn); ps += sv[i]; }
      ps += __shfl_xor(ps, 16);
      ps += __shfl_xor(ps, 32);
      l[qt] = l[qt] * c + ps;
#pragma unroll
      for (int dt = 0; dt < 2; dt++) {
        Ot[dt][qt][0] *= c; Ot[dt][qt][1] *= c;
        Ot[dt][qt][2] *= c; Ot[dt][qt][3] *= c;
      }
#pragma unroll
      for (int kt = 0; kt < 2; kt++) {
        half4 p4;
        p4[0] = (_Float16)sv[kt * 4 + 0]; p4[1] = (_Float16)sv[kt * 4 + 1];
        p4[2] = (_Float16)sv[kt * 4 + 2]; p4[3] = (_Float16)sv[kt * 4 + 3];
        pB[qt][kt] = p4;
      }
    }

#pragma unroll
    for (int qt = 0; qt < 4; qt++)
#pragma unroll
      for (int dt = 0; dt < 2; dt++)
#pragma unroll
        for (int kt = 0; kt < 2; kt++)
          Ot[dt][qt] = __builtin_amdgcn_mfma_f32_16x16x16f16(
              vA[dt][kt], pB[qt][kt], Ot[dt][qt], 0, 0, 0);
  }

#pragma unroll
  for (int qt = 0; qt < 4; qt++) {
    float inv = 1.0f / l[qt];
#pragma unroll
    for (int dt = 0; dt < 2; dt++) {
      half4 ov;
      ov[0] = (_Float16)(Ot[dt][qt][0] * inv);
      ov[1] = (_Float16)(Ot[dt][qt][1] * inv);
      ov[2] = (_Float16)(Ot[dt][qt][2] * inv);
      ov[3] = (_Float16)(Ot[dt][qt][3] * inv);
      *(half4*)(qf + qptr[qt] + dt * 16 + quad * 4) = ov;
    }
  }
}

// ============================ launch ======================================
extern "C" void kernel_launch(void* const* d_in, const int* in_sizes, int n_in,
                              void* d_out, int out_size, void* d_ws, size_t ws_size,
                              hipStream_t stream) {
  const float* x_wsa      = (const float*)d_in[0];
  const float* x_orig     = (const float*)d_in[1];
  const float* q_w        = (const float*)d_in[2];
  const float* q_b        = (const float*)d_in[3];
  const float* kv_w       = (const float*)d_in[4];
  const float* kv_b       = (const float*)d_in[5];
  const float* out_w      = (const float*)d_in[6];
  const float* out_b      = (const float*)d_in[7];
  const float* bias_table = (const float*)d_in[8];
  const float* rezero     = (const float*)d_in[9];
  float* out = (float*)d_out;

  _Float16* qf    = (_Float16*)d_ws;                            // 32 MB (q, then o in-place)
  _Float16* kvbuf = (_Float16*)((char*)d_ws + 33554432);        // 64 MB
  _Float16* wTc   = (_Float16*)((char*)d_ws + 100663296);       // conv wT, 0.8 MB
  _Float16* qwT   = (_Float16*)((char*)d_ws + 101711872);       // 128 KB
  _Float16* owT   = (_Float16*)((char*)d_ws + 101974016);       // 128 KB

  transpose_w_kernel<<<256, 256, 0, stream>>>(q_w, qwT);
  transpose_w_kernel<<<256, 256, 0, stream>>>(out_w, owT);
  wt_kernel<<<25, 512, 0, stream>>>(kv_w, wTc);

  gemm_mfma_kernel<false, true><<<dim3(512, 2), 256, 0, stream>>>(
      x_wsa, qwT, q_b, nullptr, qf);

  conv_mfma_kernel<<<dim3(64, 8, 4), 256, 0, stream>>>(x_orig, wTc, kv_b, kvbuf);

  attn_mfma_kernel<<<dim3(256, 8), 256, 0, stream>>>(qf, kvbuf, bias_table);

  gemm_mfma_kernel<true, false><<<dim3(512, 2), 256, 0, stream>>>(
      qf, owT, out_b, rezero, out);
}